// Round 16
// baseline (64.262 us; speedup 1.0000x reference)
//
#include <hip/hip_runtime.h>

// Profile-HMM forward + KLD, MI355X.
// v15 = v14 with TWO batch elements per wave, v2f-packed (.x = batch 2b,
// .y = batch 2b+1). Cost model from v8/v11/v14: per-step cost ~= 460 cyc
// FIXED (8 DPP-dependent hops x ~60 cyc exposed at 1 wave/SIMD) + ~1.5
// cyc/inst. The fixed part is per-wave exposed latency -> fill it with an
// INDEPENDENT batch's work in the same wave (v12's unroll-2 failed because
// steps are dependent; batches are not). Packed f32 (v_pk_fma) halves the
// instruction count of the doubled math. 256 blocks x 64 threads.

typedef float v2f __attribute__((ext_vector_type(2)));

constexpr float LOG2E = 1.4426950408889634f;
constexpr float LN2   = 0.6931471805599453f;

__device__ __forceinline__ float exp2_hw(float x){ return __builtin_amdgcn_exp2f(x); }
__device__ __forceinline__ float log2_hw(float x){ return __builtin_amdgcn_logf(x); }
__device__ __forceinline__ float ldx(float x,int e){ return __builtin_amdgcn_ldexpf(x,e); }
__device__ __forceinline__ int   fxe(float x){ return __builtin_amdgcn_frexp_expf(x); }
// DPP wave_shr:1 — lane i gets lane i-1's src; lane 0 gets old_.
__device__ __forceinline__ int   dppi(int o,int s){ return __builtin_amdgcn_update_dpp(o,s,0x138,0xF,0xF,false); }
__device__ __forceinline__ float dppf(float o,float s){ return __int_as_float(dppi(__float_as_int(o),__float_as_int(s))); }
__device__ __forceinline__ v2f   dppv(v2f s){ v2f r; r.x = dppf(0.0f, s.x); r.y = dppf(0.0f, s.y); return r; }
// emission select: e[sym] from float4 (x,y,z,w = syms 0..3)
__device__ __forceinline__ float esel(const float4 e, int s){
    const float lo = (s & 1) ? e.y : e.x;
    const float hi = (s & 1) ? e.w : e.z;
    return (s & 2) ? hi : lo;
}

// One 2-col step for BOTH batches. FRESH packs b0 syms in bits 0-3, b1 in 8-11.
#define STEP(FRESH, ISS1, MASKED, SM1) do {                                    \
    /* ---- cross-lane reads (independent) ---- */                             \
    const v2f qmM = dppv(emM);           /* neighbor k0 @ col c   */           \
    const v2f qmI = dppv(emI);                                                 \
    const v2f qmD = dppv(emD);                                                 \
    const v2f qeM = dppv(cMy);           /* neighbor k0 @ col c+1 */           \
    const v2f qeI = dppv(cIy);                                                 \
    const v2f qeD = dppv(cDy);                                                 \
    const int qE0 = dppi(E0, E0);        /* lane0: own E -> sq=1 exact */      \
    const int qE1 = dppi(E1, E1);                                              \
    const int qsym = dppi((FRESH), symq);                                      \
    /* ---- prev-state-only chains + scale factors ---- */                     \
    const v2f v   = (ISS1) ? q1g : gg * u;        /* fI0[2s-1] */              \
    const v2f nI1 = tmi1 * cMx + tii1 * cIx;                                   \
    const v2f nI2 = tmi2 * cMy + tii2 * cIy;                                   \
    v2f sqv; sqv.x = ldx(1.0f, qE0 - E0); sqv.y = ldx(1.0f, qE1 - E1);         \
    v2f spv; spv.x = ldx(1.0f, pE0 - E0); spv.y = ldx(1.0f, pE1 - E1);         \
    v2f tPI; tPI.x = ldx(u.x, EI00 - E0); tPI.y = ldx(u.y, EI01 - E1);         \
    v2f tmIv; tmIv.x = ldx(v.x, EI00 - E0); tmIv.y = ldx(v.y, EI01 - E1);      \
    /* ---- scale conversions ---- */                                          \
    const v2f mM  = qmM * sqv;           /* lane0: 0 * 1 = 0 */                \
    const v2f mD  = qmD * sqv;                                                 \
    const v2f eM_ = qeM * sqv;                                                 \
    const v2f eD_ = qeD * sqv;                                                 \
    const v2f PM  = pM * spv;            /* step1 lane0: 1*2^-E = fM[0][0] */  \
    const v2f PD  = pD * spv;                                                  \
    v2f mI = qmI * sqv, PI = pI * spv;                                         \
    if (lane0) { mI = tmIv; PI = tPI; }                                        \
    /* ---- emission selects (per batch; syms differ) ---- */                  \
    const int sA = qsym & 15, sB = (qsym >> 8) & 15;                           \
    v2f e1c; e1c.x = esel(el1A, sA & 3);        e1c.y = esel(el1B, sB & 3);    \
    v2f e2c; e2c.x = esel(el2A, sA & 3);        e2c.y = esel(el2B, sB & 3);    \
    v2f e1d; e1d.x = esel(el1A, (sA >> 2) & 3); e1d.y = esel(el1B, (sB >> 2) & 3); \
    v2f e2d; e2d.x = esel(el2A, (sA >> 2) & 3); e2d.y = esel(el2B, (sB >> 2) & 3); \
    /* ---- col c ---- */                                                      \
    const v2f nM1 = e1c * (tdm0 * PD  + (tim0 * PI  + tmm0 * PM));             \
    const v2f nM2 = e2c * (tdm1 * cDx + (tim1 * cIx + tmm1 * cMx));            \
    const v2f nD1 = tmd0 * mM + tdd0 * mD;                                     \
    const v2f nD2 = tmd1 * nM1 + tdd1 * nD1;                                   \
    /* ---- col c+1 ---- */                                                    \
    const v2f nM1b = e1d * (tdm0 * mD  + (tim0 * mI  + tmm0 * mM));            \
    const v2f nI1b = tmi1 * nM1 + tii1 * nI1;                                  \
    const v2f nI2b = tmi2 * nM2 + tii2 * nI2;                                  \
    const v2f nD1b = tmd0 * eM_ + tdd0 * eD_;                                  \
    const v2f nM2b = e2d * (tdm1 * nD1 + (tim1 * nI1 + tmm1 * nM1));           \
    const v2f nD2b = tmd1 * nM1b + tdd1 * nD1b;                                \
    /* ---- commit ---- */                                                     \
    emM = nM2; emI = nI2; emD = nD2;      /* mid exports (unmasked) */         \
    if (MASKED) {                                                              \
        const bool act = ((unsigned)((SM1) - i)) < 128u;                       \
        cMx = act ? nM1b : cMx;  cMy = act ? nM2b : cMy;                       \
        cIx = act ? nI1b : cIx;  cIy = act ? nI2b : cIy;                       \
        cDx = act ? nD1b : cDx;  cDy = act ? nD2b : cDy;                       \
    } else {                                                                   \
        cMx = nM1b; cMy = nM2b; cIx = nI1b; cIy = nI2b; cDx = nD1b; cDy = nD2b;\
    }                                                                          \
    pM = qeM; pI = qeI; pD = qeD; pE0 = qE0; pE1 = qE1;                        \
    symq = qsym;                                                               \
    u = gg * v;                            /* fI0[2s] */                       \
} while (0)

#define RESCALE do {                                                           \
    const float ancA = fmaxf(fmaxf(fmaxf(cMx.x, cMy.x), fmaxf(cIx.x, cIy.x)),  \
                             fmaxf(cDx.x, cDy.x));                             \
    const float ancB = fmaxf(fmaxf(fmaxf(cMx.y, cMy.y), fmaxf(cIx.y, cIy.y)),  \
                             fmaxf(cDx.y, cDy.y));                             \
    const int eA = fxe(ancA), eB = fxe(ancB);                                  \
    E0 += eA; E1 += eB;                                                        \
    v2f sE; sE.x = ldx(1.0f, -eA); sE.y = ldx(1.0f, -eB);                      \
    cMx *= sE; cMy *= sE; cIx *= sE; cIy *= sE; cDx *= sE; cDy *= sE;          \
    emM *= sE; emI *= sE; emD *= sE;                                           \
    const int eIA = fxe(u.x); EI00 += eIA;                                     \
    const int eIB = fxe(u.y); EI01 += eIB;                                     \
    u.x = ldx(u.x, -eIA); u.y = ldx(u.y, -eIB);                                \
} while (0)

// transitions: (B, 129, 7)  M2M=0 M2I=1 M2D=2 I2M=3 I2I=4 D2M=5 D2D=6
// emissions:   (B, 128, 4);  tokens: (B, 256) int32 in [0,4)
__global__ __launch_bounds__(64, 1) void phmm_fwd(const int* __restrict__ tokens,
                                                  const float* __restrict__ trans,
                                                  const float* __restrict__ emis,
                                                  float* __restrict__ nll_out)
{
    const int b = blockIdx.x;           // handles batches 2b (A/.x) and 2b+1 (B/.y)
    const int i = threadIdx.x;
    const bool lane0 = (i == 0);

    const float* abA = trans + (size_t)(2*b) * 903;
    const float* abB = trans + (size_t)(2*b+1) * 903;
    const int r0 = (2*i)*7, r1 = (2*i+1)*7, r2 = (2*i+2)*7;

    // Linear-space params (exp hoisted to init), packed {A,B}.
#define LD2(expr_r) (v2f){ exp2_hw(abA[expr_r]*LOG2E), exp2_hw(abB[expr_r]*LOG2E) }
    const v2f tmm0 = LD2(r0+0), tim0 = LD2(r0+3), tdm0 = LD2(r0+5);
    const v2f tmd0 = LD2(r0+2), tdd0 = LD2(r0+6);
    const v2f tmm1 = LD2(r1+0), tim1 = LD2(r1+3), tdm1 = LD2(r1+5);
    const v2f tmd1 = LD2(r1+2), tdd1 = LD2(r1+6);
    const v2f tmi1 = 0.25f*LD2(r1+1), tii1 = 0.25f*LD2(r1+4);
    const v2f tmi2 = 0.25f*LD2(r2+1), tii2 = 0.25f*LD2(r2+4);
    const v2f q1g  = 0.25f*LD2(1), gg = 0.25f*LD2(4);
    const v2f tKmm = LD2(128*7+0), tKim = LD2(128*7+3), tKdm = LD2(128*7+5);
#undef LD2

    const float4* ebA = (const float4*)(emis + (size_t)(2*b)*512);
    const float4* ebB = (const float4*)(emis + (size_t)(2*b+1)*512);
    float4 el1A = ebA[2*i], el2A = ebA[2*i+1];
    float4 el1B = ebB[2*i], el2B = ebB[2*i+1];
    el1A.x=exp2_hw(el1A.x*LOG2E); el1A.y=exp2_hw(el1A.y*LOG2E);
    el1A.z=exp2_hw(el1A.z*LOG2E); el1A.w=exp2_hw(el1A.w*LOG2E);
    el2A.x=exp2_hw(el2A.x*LOG2E); el2A.y=exp2_hw(el2A.y*LOG2E);
    el2A.z=exp2_hw(el2A.z*LOG2E); el2A.w=exp2_hw(el2A.w*LOG2E);
    el1B.x=exp2_hw(el1B.x*LOG2E); el1B.y=exp2_hw(el1B.y*LOG2E);
    el1B.z=exp2_hw(el1B.z*LOG2E); el1B.w=exp2_hw(el1B.w*LOG2E);
    el2B.x=exp2_hw(el2B.x*LOG2E); el2B.y=exp2_hw(el2B.y*LOG2E);
    el2B.z=exp2_hw(el2B.z*LOG2E); el2B.w=exp2_hw(el2B.w*LOG2E);

    const int4 tsA = ((const int4*)(tokens + (size_t)(2*b)*256))[i];
    const int4 tsB = ((const int4*)(tokens + (size_t)(2*b+1)*256))[i];

    // Col-0 delete chains, closed form (log2 prefix scan), per batch.
    const float ldd0A = abA[r0+6]*LOG2E, ldd1A = abA[r1+6]*LOG2E;
    const float ldd0B = abB[r0+6]*LOG2E, ldd1B = abB[r1+6]*LOG2E;
    float inclA = (lane0 ? 0.0f : ldd0A) + ldd1A;
    float inclB = (lane0 ? 0.0f : ldd0B) + ldd1B;
    #pragma unroll
    for (int d = 1; d < 64; d <<= 1) {
        const float tA = __shfl_up(inclA, d);
        const float tB = __shfl_up(inclB, d);
        if (i >= d) { inclA += tA; inclB += tB; }
    }
    float exPreA = __shfl_up(inclA, 1);
    float exPreB = __shfl_up(inclB, 1);
    if (lane0) { exPreA = 0.0f; exPreB = 0.0f; }
    const float g1A = abA[2]*LOG2E + exPreA + (lane0 ? 0.0f : ldd0A);
    const float g2A = g1A + ldd1A;
    const float g1B = abB[2]*LOG2E + exPreB + (lane0 ? 0.0f : ldd0B);
    const float g2B = g1B + ldd1B;

    int E0 = (int)floorf(fmaxf(g1A, g2A));
    int E1 = (int)floorf(fmaxf(g1B, g2B));
    v2f cMx = {0,0}, cMy = {0,0}, cIx = {0,0}, cIy = {0,0};
    v2f cDx; cDx.x = exp2_hw(g1A - (float)E0); cDx.y = exp2_hw(g1B - (float)E1);
    v2f cDy; cDy.x = exp2_hw(g2A - (float)E0); cDy.y = exp2_hw(g2B - (float)E1);
    v2f emM = {0,0}, emI = {0,0}, emD = {0,0};
    v2f pM = lane0 ? (v2f){1.0f,1.0f} : (v2f){0,0};  // with pE=0: PM=2^-E at s=1
    v2f pI = {0,0}, pD = {0,0};
    int pE0 = 0, pE1 = 0;
    v2f u = {0,0};
    int EI00 = 0, EI01 = 0;
    int symq = 0;

    // 48 groups x 4 steps (s = 1..192). Fill g<16 (masked), steady 16..31
    // (mask-free), drain 32..47 (masked, no tokens).
    #pragma unroll 1
    for (int g = 0; g < 16; ++g) {          // FILL
        const int a0A = __builtin_amdgcn_readlane(tsA.x, 2*g);
        const int a1A = __builtin_amdgcn_readlane(tsA.y, 2*g);
        const int a2A = __builtin_amdgcn_readlane(tsA.z, 2*g);
        const int a3A = __builtin_amdgcn_readlane(tsA.w, 2*g);
        const int b0A = __builtin_amdgcn_readlane(tsA.x, 2*g+1);
        const int b1A = __builtin_amdgcn_readlane(tsA.y, 2*g+1);
        const int b2A = __builtin_amdgcn_readlane(tsA.z, 2*g+1);
        const int b3A = __builtin_amdgcn_readlane(tsA.w, 2*g+1);
        const int a0B = __builtin_amdgcn_readlane(tsB.x, 2*g);
        const int a1B = __builtin_amdgcn_readlane(tsB.y, 2*g);
        const int a2B = __builtin_amdgcn_readlane(tsB.z, 2*g);
        const int a3B = __builtin_amdgcn_readlane(tsB.w, 2*g);
        const int b0B = __builtin_amdgcn_readlane(tsB.x, 2*g+1);
        const int b1B = __builtin_amdgcn_readlane(tsB.y, 2*g+1);
        const int b2B = __builtin_amdgcn_readlane(tsB.z, 2*g+1);
        const int b3B = __builtin_amdgcn_readlane(tsB.w, 2*g+1);
        STEP((a0A|(a1A<<2)) | ((a0B|(a1B<<2))<<8), g == 0, 1, 4*g);
        STEP((a2A|(a3A<<2)) | ((a2B|(a3B<<2))<<8), false,  1, 4*g + 1);
        STEP((b0A|(b1A<<2)) | ((b0B|(b1B<<2))<<8), false,  1, 4*g + 2);
        STEP((b2A|(b3A<<2)) | ((b2B|(b3B<<2))<<8), false,  1, 4*g + 3);
        RESCALE;
    }
    #pragma unroll 1
    for (int g = 16; g < 32; ++g) {         // STEADY (all lanes active)
        const int a0A = __builtin_amdgcn_readlane(tsA.x, 2*g);
        const int a1A = __builtin_amdgcn_readlane(tsA.y, 2*g);
        const int a2A = __builtin_amdgcn_readlane(tsA.z, 2*g);
        const int a3A = __builtin_amdgcn_readlane(tsA.w, 2*g);
        const int b0A = __builtin_amdgcn_readlane(tsA.x, 2*g+1);
        const int b1A = __builtin_amdgcn_readlane(tsA.y, 2*g+1);
        const int b2A = __builtin_amdgcn_readlane(tsA.z, 2*g+1);
        const int b3A = __builtin_amdgcn_readlane(tsA.w, 2*g+1);
        const int a0B = __builtin_amdgcn_readlane(tsB.x, 2*g);
        const int a1B = __builtin_amdgcn_readlane(tsB.y, 2*g);
        const int a2B = __builtin_amdgcn_readlane(tsB.z, 2*g);
        const int a3B = __builtin_amdgcn_readlane(tsB.w, 2*g);
        const int b0B = __builtin_amdgcn_readlane(tsB.x, 2*g+1);
        const int b1B = __builtin_amdgcn_readlane(tsB.y, 2*g+1);
        const int b2B = __builtin_amdgcn_readlane(tsB.z, 2*g+1);
        const int b3B = __builtin_amdgcn_readlane(tsB.w, 2*g+1);
        STEP((a0A|(a1A<<2)) | ((a0B|(a1B<<2))<<8), false, 0, 4*g);
        STEP((a2A|(a3A<<2)) | ((a2B|(a3B<<2))<<8), false, 0, 4*g + 1);
        STEP((b0A|(b1A<<2)) | ((b0B|(b1B<<2))<<8), false, 0, 4*g + 2);
        STEP((b2A|(b3A<<2)) | ((b2B|(b3B<<2))<<8), false, 0, 4*g + 3);
        RESCALE;
    }
    #pragma unroll 1
    for (int g = 32; g < 48; ++g) {         // DRAIN (no fresh tokens needed)
        STEP(0, false, 1, 4*g);
        STEP(0, false, 1, 4*g + 1);
        STEP(0, false, 1, 4*g + 2);
        STEP(0, false, 1, 4*g + 3);
        RESCALE;
    }

    // lane 63 holds k=127,128 @ col 256; y-col = k=128 in cMy/cIy/cDy.
    const v2f fin = tKdm * cDy + (tKim * cIy + tKmm * cMy);
    if (i == 63) {
        nll_out[2*b]   = -(log2_hw(fin.x) + (float)E0) * LN2;
        nll_out[2*b+1] = -(log2_hw(fin.y) + (float)E1) * LN2;
    }
}

__global__ __launch_bounds__(256) void phmm_finish(const float* __restrict__ nll,
                                                   const float* __restrict__ mus,
                                                   const float* __restrict__ logvars,
                                                   float* __restrict__ out)
{
    const int tid = threadIdx.x;
    float acc = 0.0f;
    for (int idx = tid; idx < 512; idx += 256) acc += nll[idx];
    for (int idx = tid; idx < 8192; idx += 256) {
        const float mu = mus[idx], lv = logvars[idx];
        acc -= 0.5f * (1.0f + lv - mu * mu - exp2_hw(lv * LOG2E));
    }
    #pragma unroll
    for (int off = 32; off >= 1; off >>= 1) acc += __shfl_down(acc, off);
    __shared__ float red[4];
    if ((tid & 63) == 0) red[tid >> 6] = acc;
    __syncthreads();
    if (tid == 0) out[0] = (red[0] + red[1] + red[2] + red[3]) * (1.0f / 512.0f);
}

extern "C" void kernel_launch(void* const* d_in, const int* in_sizes, int n_in,
                              void* d_out, int out_size, void* d_ws, size_t ws_size,
                              hipStream_t stream)
{
    const int*   tokens  = (const int*)d_in[0];   // (512, 256) int32
    const float* trans   = (const float*)d_in[1]; // (512, 129, 7) f32
    const float* emis    = (const float*)d_in[2]; // (512, 128, 4) f32
    const float* mus     = (const float*)d_in[3]; // (512, 16) f32
    const float* logvars = (const float*)d_in[4]; // (512, 16) f32
    float* nll = (float*)d_ws;                    // 512 floats scratch

    phmm_fwd<<<dim3(256), dim3(64), 0, stream>>>(tokens, trans, emis, nll);
    phmm_finish<<<dim3(1), dim3(256), 0, stream>>>(nll, mus, logvars, (float*)d_out);
}

// Round 17
// 40.792 us; speedup vs baseline: 1.5754x; 1.5754x over previous
//
#include <hip/hip_runtime.h>

// Profile-HMM forward + KLD, MI355X.
// v16 = v14 skeleton (1 batch/wave, 2 cols/step, 192 steps, linear space,
// per-lane exponent E) with the boundary channel COMPRESSED:
// measured law (v8/v14/v15): step cost ~= 65 cyc x #cross-lane ops,
// independence irrelevant, VALU hidden. So send the MINIMUM information:
// the sender pre-combines its k2-row state with the NEXT row's transition
// coefficients (a[2i+2], which the sender loads at init) into 2 dots per
// column: dotM = t2mm*fM + t2im*fI + t2dm*fD, dotD = t2md*fM + t2dd*fD.
// 4 dot DPPs + 1 sym DPP per step + 1 E DPP per 4-step group (E constant
// between lockstep rescales; sq hoisted) = 5.25 ops/step vs v14's 8.
// Bonus: lane 63's end-dot with row-128 coefficients IS the final
// reduction; pre-active lanes' masked-frozen xdMe carries col-0 boundary.

constexpr float LOG2E = 1.4426950408889634f;
constexpr float LN2   = 0.6931471805599453f;

__device__ __forceinline__ float exp2_hw(float x){ return __builtin_amdgcn_exp2f(x); }
__device__ __forceinline__ float log2_hw(float x){ return __builtin_amdgcn_logf(x); }
__device__ __forceinline__ float ldx(float x,int e){ return __builtin_amdgcn_ldexpf(x,e); }
__device__ __forceinline__ int   fxe(float x){ return __builtin_amdgcn_frexp_expf(x); }
// DPP wave_shr:1 — lane i gets lane i-1's src; lane 0 gets old_.
__device__ __forceinline__ int   dppi(int o,int s){ return __builtin_amdgcn_update_dpp(o,s,0x138,0xF,0xF,false); }
__device__ __forceinline__ float dppf(float o,float s){ return __int_as_float(dppi(__float_as_int(o),__float_as_int(s))); }

// One 2-col step: cols c = 2*(SM1+1)-1-2i, c+1.
// Received channels (from lane i-1, row 2i):
//   qdMm: dotM @ col c   -> nM1b (this step)
//   qdMe: dotM @ col c+1 -> saved (pdM), consumed NEXT step as dot @ c-1
//   qdDm: dotD @ col c   -> nD1
//   qdDe: dotD @ col c+1 -> nD1b
// sq = 2^(qE - E) hoisted per 4-step group (E frozen between rescales).
#define STEP(FRESH, ISS1, MASKED, SM1) do {                                    \
    const float qdMm = dppf(0.0f, xdMm);                                       \
    const float qdMe = dppf(0.0f, xdMe);                                       \
    const float qdDm = dppf(0.0f, xdDm);                                       \
    const float qdDe = dppf(0.0f, xdDe);                                       \
    const int   qsym = dppi((FRESH), symq);                                    \
    const float v   = (ISS1) ? q1g : gg * u;       /* fI0[2s-1] */             \
    const float nI1 = fmaf(tmi1, cMx, tii1 * cIx);                             \
    const float nI2 = fmaf(tmi2, cMy, tii2 * cIy);                             \
    float dM_c1 = qdMm * sq;                                                   \
    const float dD_c  = qdDm * sq;     /* lane0: 0*1 = 0 = row-0 dotD */       \
    const float dD_c1 = qdDe * sq;                                             \
    const float dM_sv = qdMe * sq;                                             \
    float dP = pdM;                                                            \
    /* lane-0 virtual row 0: dotM = tmm0*fM0 + tim0*fI0 (fD0-term = 0) */      \
    const float z0 = fmaf(tim0, ldx(u, EI0 - E),                               \
                          (ISS1) ? ldx(tmm0, -E) : 0.0f);                      \
    const float z1 = tim0 * ldx(v, EI0 - E);                                   \
    if (lane0) { dP = z0; dM_c1 = z1; }                                        \
    const bool ba = (qsym & 1) != 0, bb = (qsym & 2) != 0;                     \
    const bool bc = (qsym & 4) != 0, bd = (qsym & 8) != 0;                     \
    const float e1c = bb ? (ba ? el1.w : el1.z) : (ba ? el1.y : el1.x);        \
    const float e2c = bb ? (ba ? el2.w : el2.z) : (ba ? el2.y : el2.x);        \
    const float e1d = bd ? (bc ? el1.w : el1.z) : (bc ? el1.y : el1.x);        \
    const float e2d = bd ? (bc ? el2.w : el2.z) : (bc ? el2.y : el2.x);        \
    /* ---- col c ---- */                                                      \
    const float nM1 = e1c * dP;                                                \
    const float nM2 = e2c * fmaf(tdm1, cDx, fmaf(tim1, cIx, tmm1 * cMx));      \
    const float nD1 = dD_c;                                                    \
    const float nD2 = fmaf(tmd1, nM1, tdd1 * nD1);                             \
    /* ---- col c+1 ---- */                                                    \
    const float nM1b = e1d * dM_c1;                                            \
    const float nI1b = fmaf(tmi1, nM1, tii1 * nI1);                            \
    const float nI2b = fmaf(tmi2, nM2, tii2 * nI2);                            \
    const float nD1b = dD_c1;                                                  \
    const float nM2b = e2d * fmaf(tdm1, nD1, fmaf(tim1, nI1, tmm1 * nM1));     \
    const float nD2b = fmaf(tmd1, nM1b, tdd1 * nD1b);                          \
    /* ---- sender dots for lane i+1 (row 2i+2 coefficients) ---- */           \
    const float ndMm = fmaf(t2mm, nM2,  fmaf(t2im, nI2,  t2dm * nD2));         \
    const float ndMe = fmaf(t2mm, nM2b, fmaf(t2im, nI2b, t2dm * nD2b));        \
    const float ndDm = fmaf(t2md, nM2,  t2dd * nD2);                           \
    const float ndDe = fmaf(t2md, nM2b, t2dd * nD2b);                          \
    /* ---- commit ---- */                                                     \
    xdMm = ndMm; xdDm = ndDm; xdDe = ndDe;  /* consumed only when act ✓ */     \
    if (MASKED) {                                                              \
        const bool act = ((unsigned)((SM1) - i)) < 128u;                       \
        cMx = act ? nM1b : cMx;  cMy = act ? nM2b : cMy;                       \
        cIx = act ? nI1b : cIx;  cIy = act ? nI2b : cIy;                       \
        cDx = act ? nD1b : cDx;  cDy = act ? nD2b : cDy;                       \
        xdMe = act ? ndMe : xdMe;   /* pre-active: frozen col-0 end-dot */     \
    } else {                                                                   \
        cMx = nM1b; cMy = nM2b; cIx = nI1b; cIy = nI2b; cDx = nD1b; cDy = nD2b;\
        xdMe = ndMe;                                                           \
    }                                                                          \
    pdM = dM_sv;                                                               \
    symq = qsym;                                                               \
    u = gg * v;                                    /* fI0[2s] */               \
} while (0)

#define RESCALE do {                                                           \
    const float anc = fmaxf(fmaxf(fmaxf(cMx, cMy), fmaxf(cIx, cIy)),           \
                            fmaxf(cDx, cDy));                                  \
    const int e = fxe(anc);                                                    \
    E += e;                                                                    \
    const float sE = ldx(1.0f, -e);                                            \
    cMx *= sE; cMy *= sE; cIx *= sE; cIy *= sE; cDx *= sE; cDy *= sE;          \
    xdMm *= sE; xdMe *= sE; xdDm *= sE; xdDe *= sE; pdM *= sE;                 \
    const int eI = fxe(u); EI0 += eI; u = ldx(u, -eI);                         \
} while (0)

// transitions: (B, 129, 7)  M2M=0 M2I=1 M2D=2 I2M=3 I2I=4 D2M=5 D2D=6
// emissions:   (B, 128, 4);  tokens: (B, 256) int32 in [0,4)
__global__ __launch_bounds__(64, 1) void phmm_fwd(const int* __restrict__ tokens,
                                                  const float* __restrict__ trans,
                                                  const float* __restrict__ emis,
                                                  float* __restrict__ nll_out)
{
    const int b = blockIdx.x;
    const int i = threadIdx.x;
    const bool lane0 = (i == 0);

    const float* ab = trans + (size_t)b * 903;
    const int r0 = (2*i)*7, r1 = (2*i+1)*7, r2 = (2*i+2)*7;

    // Linear-space params.
    const float tmm0 = exp2_hw(ab[r0+0]*LOG2E);      // lane-0 synthesis only
    const float tim0 = exp2_hw(ab[r0+3]*LOG2E);
    const float tmm1 = exp2_hw(ab[r1+0]*LOG2E);
    const float tim1 = exp2_hw(ab[r1+3]*LOG2E);
    const float tdm1 = exp2_hw(ab[r1+5]*LOG2E);
    const float tmd1 = exp2_hw(ab[r1+2]*LOG2E);
    const float tdd1 = exp2_hw(ab[r1+6]*LOG2E);
    const float tmi1 = 0.25f*exp2_hw(ab[r1+1]*LOG2E);
    const float tii1 = 0.25f*exp2_hw(ab[r1+4]*LOG2E);
    const float tmi2 = 0.25f*exp2_hw(ab[r2+1]*LOG2E);
    const float tii2 = 0.25f*exp2_hw(ab[r2+4]*LOG2E);
    // Sender-dot coefficients: row 2i+2 = receiver's (k-1) row.
    const float t2mm = exp2_hw(ab[r2+0]*LOG2E);
    const float t2im = exp2_hw(ab[r2+3]*LOG2E);
    const float t2dm = exp2_hw(ab[r2+5]*LOG2E);
    const float t2md = exp2_hw(ab[r2+2]*LOG2E);
    const float t2dd = exp2_hw(ab[r2+6]*LOG2E);
    const float q1g  = 0.25f*exp2_hw(ab[1]*LOG2E);   // fI0[1]
    const float gg   = 0.25f*exp2_hw(ab[4]*LOG2E);   // fI0 geometric link

    const float4* eb = (const float4*)(emis + (size_t)b*512);
    float4 el1 = eb[2*i], el2 = eb[2*i+1];
    el1.x=exp2_hw(el1.x*LOG2E); el1.y=exp2_hw(el1.y*LOG2E);
    el1.z=exp2_hw(el1.z*LOG2E); el1.w=exp2_hw(el1.w*LOG2E);
    el2.x=exp2_hw(el2.x*LOG2E); el2.y=exp2_hw(el2.y*LOG2E);
    el2.z=exp2_hw(el2.z*LOG2E); el2.w=exp2_hw(el2.w*LOG2E);

    const int4 ts = ((const int4*)(tokens + (size_t)b*256))[i];

    // Col-0 delete chain, closed form (log2 prefix scan).
    const float ldd0 = ab[r0+6]*LOG2E;
    const float ldd1 = ab[r1+6]*LOG2E;
    const float lmd0b = ab[2]*LOG2E;
    float incl = (lane0 ? 0.0f : ldd0) + ldd1;
    #pragma unroll
    for (int d = 1; d < 64; d <<= 1) {
        float t = __shfl_up(incl, d);
        if (i >= d) incl += t;
    }
    float exPre = __shfl_up(incl, 1);
    if (lane0) exPre = 0.0f;
    const float g1 = lmd0b + exPre + (lane0 ? 0.0f : ldd0); // log2 fD[2i+1][0]
    const float g2 = g1 + ldd1;                             // log2 fD[2i+2][0]

    int E = (int)floorf(fmaxf(g1, g2));
    float cMx = 0.0f, cMy = 0.0f, cIx = 0.0f, cIy = 0.0f;
    float cDx = exp2_hw(g1 - (float)E), cDy = exp2_hw(g2 - (float)E);
    // Export regs. xdMe init = col-0 end-dot (fM[2i+2][0]=0, fI=0):
    float xdMm = 0.0f, xdDm = 0.0f, xdDe = 0.0f;
    float xdMe = t2dm * cDy;
    float pdM = 0.0f;                 // never consumed before first real save
    float u = 0.0f; int EI0 = 0;      // fI0 chain (wave-replicated)
    int symq = 0;

    // 48 groups x 4 steps (s = 1..192). Fill g<16 (masked), steady 16..31
    // (mask-free), drain 32..47 (masked, no tokens). qE/sq hoisted per group.
    #pragma unroll 1
    for (int g = 0; g < 16; ++g) {          // FILL
        const int qE = dppi(E, E);
        const float sq = ldx(1.0f, qE - E);
        const int a0 = __builtin_amdgcn_readlane(ts.x, 2*g);
        const int a1 = __builtin_amdgcn_readlane(ts.y, 2*g);
        const int a2 = __builtin_amdgcn_readlane(ts.z, 2*g);
        const int a3 = __builtin_amdgcn_readlane(ts.w, 2*g);
        const int b0 = __builtin_amdgcn_readlane(ts.x, 2*g+1);
        const int b1 = __builtin_amdgcn_readlane(ts.y, 2*g+1);
        const int b2 = __builtin_amdgcn_readlane(ts.z, 2*g+1);
        const int b3 = __builtin_amdgcn_readlane(ts.w, 2*g+1);
        STEP(a0 | (a1 << 2), g == 0, 1, 4*g);
        STEP(a2 | (a3 << 2), false,  1, 4*g + 1);
        STEP(b0 | (b1 << 2), false,  1, 4*g + 2);
        STEP(b2 | (b3 << 2), false,  1, 4*g + 3);
        RESCALE;
    }
    #pragma unroll 1
    for (int g = 16; g < 32; ++g) {         // STEADY (all lanes active)
        const int qE = dppi(E, E);
        const float sq = ldx(1.0f, qE - E);
        const int a0 = __builtin_amdgcn_readlane(ts.x, 2*g);
        const int a1 = __builtin_amdgcn_readlane(ts.y, 2*g);
        const int a2 = __builtin_amdgcn_readlane(ts.z, 2*g);
        const int a3 = __builtin_amdgcn_readlane(ts.w, 2*g);
        const int b0 = __builtin_amdgcn_readlane(ts.x, 2*g+1);
        const int b1 = __builtin_amdgcn_readlane(ts.y, 2*g+1);
        const int b2 = __builtin_amdgcn_readlane(ts.z, 2*g+1);
        const int b3 = __builtin_amdgcn_readlane(ts.w, 2*g+1);
        STEP(a0 | (a1 << 2), false, 0, 4*g);
        STEP(a2 | (a3 << 2), false, 0, 4*g + 1);
        STEP(b0 | (b1 << 2), false, 0, 4*g + 2);
        STEP(b2 | (b3 << 2), false, 0, 4*g + 3);
        RESCALE;
    }
    #pragma unroll 1
    for (int g = 32; g < 48; ++g) {         // DRAIN (no fresh tokens needed)
        const int qE = dppi(E, E);
        const float sq = ldx(1.0f, qE - E);
        STEP(0, false, 1, 4*g);
        STEP(0, false, 1, 4*g + 1);
        STEP(0, false, 1, 4*g + 2);
        STEP(0, false, 1, 4*g + 3);
        RESCALE;
    }

    // lane 63: xdMe (frozen after its last active step, rescales tracked by E)
    // = a[128][M2M]*fM[128][256] + a[128][I2M]*fI + a[128][D2M]*fD = final sum.
    if (i == 63) nll_out[b] = -(log2_hw(xdMe) + (float)E)*LN2;
}

__global__ __launch_bounds__(256) void phmm_finish(const float* __restrict__ nll,
                                                   const float* __restrict__ mus,
                                                   const float* __restrict__ logvars,
                                                   float* __restrict__ out)
{
    const int tid = threadIdx.x;
    float acc = 0.0f;
    for (int idx = tid; idx < 512; idx += 256) acc += nll[idx];
    for (int idx = tid; idx < 8192; idx += 256) {
        const float mu = mus[idx], lv = logvars[idx];
        acc -= 0.5f * (1.0f + lv - mu * mu - exp2_hw(lv * LOG2E));
    }
    #pragma unroll
    for (int off = 32; off >= 1; off >>= 1) acc += __shfl_down(acc, off);
    __shared__ float red[4];
    if ((tid & 63) == 0) red[tid >> 6] = acc;
    __syncthreads();
    if (tid == 0) out[0] = (red[0] + red[1] + red[2] + red[3]) * (1.0f / 512.0f);
}

extern "C" void kernel_launch(void* const* d_in, const int* in_sizes, int n_in,
                              void* d_out, int out_size, void* d_ws, size_t ws_size,
                              hipStream_t stream)
{
    const int*   tokens  = (const int*)d_in[0];   // (512, 256) int32
    const float* trans   = (const float*)d_in[1]; // (512, 129, 7) f32
    const float* emis    = (const float*)d_in[2]; // (512, 128, 4) f32
    const float* mus     = (const float*)d_in[3]; // (512, 16) f32
    const float* logvars = (const float*)d_in[4]; // (512, 16) f32
    float* nll = (float*)d_ws;                    // 512 floats scratch

    phmm_fwd<<<dim3(512), dim3(64), 0, stream>>>(tokens, trans, emis, nll);
    phmm_finish<<<dim3(1), dim3(256), 0, stream>>>(nll, mus, logvars, (float*)d_out);
}